// Round 5
// baseline (9572.840 us; speedup 1.0000x reference)
//
#include <hip/hip_runtime.h>
#include <math.h>

// LSTM anomaly scan, B=256 T=1024 I=8 H=164 O=1, WL=0, THRESH=0.1.
// One block (704 thr = 11 waves) per batch element, sequential t-loop.
// Thread j owns gate row j.
//
// Model history: r3->r4 proved the L2 weight stream is FREE at <=189KB/step
// (halving it moved dur 0.5%). VGPR=76 with 72 pinned floats => weights sit
// in the unified-file AGPR side (VALU sources AGPR directly) — residency
// works. Remaining per-step costs: VALU ~2300cy/SIMD (164 readlane +
// 172 FMA + epilogue), LDS pipe ~2800cy of which WEIGHT TAIL READS are
// 1980cy, interleaved with FMAs => exposed lgkm waits at 2.75 waves/SIMD.
// This round: ALL-STREAM — 100 non-pinned cols (25 dwordx4/thread/step,
// 262KB/step/block ~= 2.9TB/s per XCD < 4.3 ceiling) and LDS shrinks to
// the 5KB gate buffer. Deletes the LDS-tail pipe work + all weight lgkm
// stalls from the matvec phase. Also: branchless activation
// m*sigma(m*acc)+(1-m) (m=2 for tanh rows) removes the divergent dual
// path in gate-boundary waves.
// Skeleton (proven, absmax 2.44e-4): ONE barrier/step, flat gate LDS
// (0 conflicts), h broadcast via v_readlane of redundant per-wave state,
// DPP wave-sum pred, rcp+Newton activations with overflow clamp.

typedef __attribute__((ext_vector_type(4))) float f4;

namespace {
constexpr int kB = 256;
constexpr int kT = 1024;
constexpr int kI = 8;
constexpr int kH = 164;
constexpr int kG = 4 * kH;                     // 656
constexpr int kThreads = 704;                  // 11 waves
constexpr int kRegC = 16;                      // pinned f4 groups (cols 0..63)
constexpr int kStrBase = kRegC * 4;            // 64
constexpr int kStrC = (kH - kStrBase) / 4;     // 25 streamed f4 groups
constexpr float kThresh = 0.1f;

__device__ __forceinline__ float rlane(float v, int l) {
    return __int_as_float(__builtin_amdgcn_readlane(__float_as_int(v), l));
}
__device__ __forceinline__ float hb(float h0, float h1, float h2, int k) {
    return (k < 64) ? rlane(h0, k)
         : (k < 128) ? rlane(h1, k - 64)
                     : rlane(h2, k - 128);
}
template <int CTRL>
__device__ __forceinline__ float dpp_add(float x) {
    int t = __builtin_amdgcn_update_dpp(0, __float_as_int(x), CTRL, 0xf, 0xf, true);
    return __int_as_float(t);
}
// full-wave sum, result broadcast via lane 63
__device__ __forceinline__ float wave_sum(float x) {
    x += dpp_add<0x111>(x);   // row_shr:1
    x += dpp_add<0x112>(x);   // row_shr:2
    x += dpp_add<0x114>(x);   // row_shr:4
    x += dpp_add<0x118>(x);   // row_shr:8
    x += dpp_add<0x142>(x);   // row_bcast:15
    x += dpp_add<0x143>(x);   // row_bcast:31
    return rlane(x, 63);
}
// rcp + one Newton iteration: ~0.5 ulp at 3 instructions
__device__ __forceinline__ float fast_rcp(float d) {
    float r = __builtin_amdgcn_rcpf(d);
    float e = fmaf(-d, r, 1.0f);
    return fmaf(r, e, r);
}
// sigma(x), overflow-safe (clamp inf exp before Newton step)
__device__ __forceinline__ float sigm_c(float x) {
    float e = fminf(__expf(-x), 3.0e38f);
    return fast_rcp(1.0f + e);
}
// tanh(x) = 2*sigma(2x) - 1
__device__ __forceinline__ float tanh_c(float x) {
    return fmaf(2.0f, sigm_c(2.0f * x), -1.0f);
}
} // namespace

__global__
__attribute__((amdgpu_flat_work_group_size(kThreads, kThreads)))
__attribute__((amdgpu_waves_per_eu(3, 3)))
void lstm_anom_kernel(
    const float* __restrict__ x,     // (B,T,I)
    const float* __restrict__ Wih,   // (4H,I)
    const float* __restrict__ Whh,   // (4H,H)
    const float* __restrict__ bih,   // (4H)
    const float* __restrict__ bhh,   // (4H)
    const float* __restrict__ Wout,  // (1,H)
    const float* __restrict__ bout,  // (1)
    float* __restrict__ out)         // preds (B,T) then flags (B,T)
{
    __shared__ float gates[2][kG];      // 5248 B total LDS

    const int tid  = threadIdx.x;
    const int lane = tid & 63;
    const int b    = blockIdx.x;
    const int jj   = (tid < kG) ? tid : (kG - 1);
    const bool is_tanh = (jj >= 2 * kH) && (jj < 3 * kH);
    // branchless activation constants: av = m*sigma(m*acc) + (1-m)
    const float am = is_tanh ? 2.0f : 1.0f;
    const float ao = 1.0f - am;

    // ---- pinned weight set: cols 0..63 (16 f4) + W_ih (2 f4) ----
    const f4* wrow = (const f4*)(Whh + (size_t)jj * kH);
    f4 w0 = wrow[0],  w1 = wrow[1],  w2 = wrow[2],  w3 = wrow[3];
    f4 w4 = wrow[4],  w5 = wrow[5],  w6 = wrow[6],  w7 = wrow[7];
    f4 w8 = wrow[8],  w9 = wrow[9],  wA = wrow[10], wB = wrow[11];
    f4 wC = wrow[12], wD = wrow[13], wE = wrow[14], wF = wrow[15];
    f4 wih0 = ((const f4*)(Wih + (size_t)jj * kI))[0];
    f4 wih1 = ((const f4*)(Wih + (size_t)jj * kI))[1];
    asm volatile("" : "+v"(w0), "+v"(w1), "+v"(w2), "+v"(w3),
                      "+v"(w4), "+v"(w5), "+v"(w6), "+v"(w7),
                      "+v"(w8), "+v"(w9), "+v"(wA), "+v"(wB),
                      "+v"(wC), "+v"(wD), "+v"(wE), "+v"(wF),
                      "+v"(wih0), "+v"(wih1));
    float bsum = bih[jj] + bhh[jj];
    const int u2 = (lane < kH - 128) ? (128 + lane) : (kH - 1); // clamp
    float wo0 = Wout[lane];
    float wo1 = Wout[64 + lane];
    float wo2 = (128 + lane < kH) ? Wout[128 + lane] : 0.0f;    // kills dup
    asm volatile("" : "+v"(bsum), "+v"(wo0), "+v"(wo1), "+v"(wo2));
    const float bo = bout[0];

    // streamed cols 64..163: 25 loads, all base + immediate offset
    const f4* ws = (const f4*)(Whh + (size_t)jj * kH + kStrBase);

    // redundant per-wave state: units lane, 64+lane, u2
    float vc0 = 0.f, vc1 = 0.f, vc2 = 0.f;
    float vh0 = 0.f, vh1 = 0.f, vh2 = 0.f;
    float pred = 0.f;

    const float* xb = x + (size_t)b * kT * kI;
    float* pred_out = out + (size_t)b * kT;
    float* flag_out = out + (size_t)kB * kT + (size_t)b * kT;

    f4 xa = ((const f4*)xb)[0];
    f4 xc = ((const f4*)xb)[1];

    __syncthreads();

    for (int t = 0; t < kT; ++t) {
        // ---- stream batches A,B issued first (consumed 2 batches later) ----
        f4 sA0 = ws[0],  sA1 = ws[1],  sA2 = ws[2],  sA3 = ws[3],  sA4 = ws[4];
        f4 sB0 = ws[5],  sB1 = ws[6],  sB2 = ws[7],  sB3 = ws[8],  sB4 = ws[9];

        const bool  anom = (t > 0) && (fabsf(pred - xa.x) > kThresh);
        const float x0e  = anom ? pred : xa.x;

        // ---- x-part: 4 independent accumulators ----
        float a0 = fmaf(x0e, wih0.x, bsum);
        float a1 = xa.y * wih0.y;
        float a2 = xa.z * wih0.z;
        float a3 = xa.w * wih0.w;
        a0 = fmaf(xc.x, wih1.x, a0);
        a1 = fmaf(xc.y, wih1.y, a1);
        a2 = fmaf(xc.z, wih1.z, a2);
        a3 = fmaf(xc.w, wih1.w, a3);

        // prefetch x[t+1]
        const f4* nx = (const f4*)(xb + (size_t)((t + 1 < kT) ? t + 1 : t) * kI);
        f4 na = nx[0];
        f4 nc = nx[1];

        #define GRP(W, KB) \
            a0 = fmaf(hb(vh0, vh1, vh2, (KB) + 0), (W).x, a0); \
            a1 = fmaf(hb(vh0, vh1, vh2, (KB) + 1), (W).y, a1); \
            a2 = fmaf(hb(vh0, vh1, vh2, (KB) + 2), (W).z, a2); \
            a3 = fmaf(hb(vh0, vh1, vh2, (KB) + 3), (W).w, a3);

        // ---- pinned FMAs (cols 0..31) under stream-A/B latency ----
        GRP(w0, 0)  GRP(w1, 4)  GRP(w2, 8)  GRP(w3, 12)
        GRP(w4, 16) GRP(w5, 20) GRP(w6, 24) GRP(w7, 28)

        // issue batch C (cols 104..123)
        f4 sC0 = ws[10], sC1 = ws[11], sC2 = ws[12], sC3 = ws[13], sC4 = ws[14];

        // ---- pinned FMAs (cols 32..63) ----
        GRP(w8, 32) GRP(w9, 36) GRP(wA, 40) GRP(wB, 44)
        GRP(wC, 48) GRP(wD, 52) GRP(wE, 56) GRP(wF, 60)

        // issue batch D (cols 124..143)
        f4 sD0 = ws[15], sD1 = ws[16], sD2 = ws[17], sD3 = ws[18], sD4 = ws[19];

        // ---- consume A (cols 64..83) ----
        GRP(sA0, 64) GRP(sA1, 68) GRP(sA2, 72) GRP(sA3, 76) GRP(sA4, 80)

        // issue batch E (cols 144..163)
        f4 sE0 = ws[20], sE1 = ws[21], sE2 = ws[22], sE3 = ws[23], sE4 = ws[24];

        // ---- consume B..E ----
        GRP(sB0, 84)  GRP(sB1, 88)  GRP(sB2, 92)  GRP(sB3, 96)  GRP(sB4, 100)
        GRP(sC0, 104) GRP(sC1, 108) GRP(sC2, 112) GRP(sC3, 116) GRP(sC4, 120)
        GRP(sD0, 124) GRP(sD1, 128) GRP(sD2, 132) GRP(sD3, 136) GRP(sD4, 140)
        GRP(sE0, 144) GRP(sE1, 148) GRP(sE2, 152) GRP(sE3, 156) GRP(sE4, 160)
        #undef GRP

        // ---- branchless activation: av = m*sigma(m*acc) + (1-m) ----
        const float acc = (a0 + a1) + (a2 + a3);
        const float av  = fmaf(am, sigm_c(am * acc), ao);

        float* gw = gates[t & 1];
        if (tid < kG) gw[jj] = av;
        __syncthreads();

        // ---- redundant cell/h update in every wave (no 2nd barrier) ----
        const float* gb = gates[t & 1];
        float iv0 = gb[lane],          iv1 = gb[64 + lane],          iv2 = gb[u2];
        float fv0 = gb[kH + lane],     fv1 = gb[kH + 64 + lane],     fv2 = gb[kH + u2];
        float gv0 = gb[2*kH + lane],   gv1 = gb[2*kH + 64 + lane],   gv2 = gb[2*kH + u2];
        float ov0 = gb[3*kH + lane],   ov1 = gb[3*kH + 64 + lane],   ov2 = gb[3*kH + u2];
        vc0 = fmaf(fv0, vc0, iv0 * gv0);  vh0 = ov0 * tanh_c(vc0);
        vc1 = fmaf(fv1, vc1, iv1 * gv1);  vh1 = ov1 * tanh_c(vc1);
        vc2 = fmaf(fv2, vc2, iv2 * gv2);  vh2 = ov2 * tanh_c(vc2);

        // ---- pred (identical in every wave; DPP reduce, VALU only) ----
        const float p = fmaf(vh0, wo0, fmaf(vh1, wo1, vh2 * wo2));
        pred = wave_sum(p) + bo;

        if (tid == 0) {
            pred_out[t] = pred;
            flag_out[t] = anom ? 1.0f : 0.0f;
        }
        xa = na;
        xc = nc;
    }
}

extern "C" void kernel_launch(void* const* d_in, const int* in_sizes, int n_in,
                              void* d_out, int out_size, void* d_ws, size_t ws_size,
                              hipStream_t stream) {
    const float* x    = (const float*)d_in[0];
    const float* Wih  = (const float*)d_in[1];
    const float* Whh  = (const float*)d_in[2];
    const float* bih  = (const float*)d_in[3];
    const float* bhh  = (const float*)d_in[4];
    const float* Wout = (const float*)d_in[5];
    const float* bout = (const float*)d_in[6];
    lstm_anom_kernel<<<dim3(kB), dim3(kThreads), 0, stream>>>(
        x, Wih, Whh, bih, bhh, Wout, bout, (float*)d_out);
}

// Round 6
// 2177.052 us; speedup vs baseline: 4.3972x; 4.3972x over previous
//
#include <hip/hip_runtime.h>
#include <math.h>

// LSTM anomaly scan, B=256 T=1024 I=8 H=164 O=1, WL=0, THRESH=0.1.
// One block (704 thr = 11 waves) per batch element, sequential t-loop.
// Thread j owns gate row j.
//
// r5 post-mortem: all-stream (25 f4/thread/step) collapsed (9573us,
// VALUBusy 28%) — allocator sank loads to use sites (VGPR=84 < 100 in
// flight), serializing 5 uncoalesced L2 round-trips/step. LDS planes are
// essential. Reverted to r4 weight economics (best, 2808us):
// 16 f4 pinned + 10 f4 streamed + 15 LDS planes.
//
// New in r6 — attack the broadcast tax (half of matvec VALU was
// v_readlane + SGPR-hazard stalls):
//  - h lives in LDS; matvec reads it with UNIFORM-address ds_read_b128
//    (hardware broadcast, conflict-free): 41 lgkm reads replace 164
//    VALU readlanes. Requires a 2nd barrier (h visibility) — accepted.
//  - v_pk_fma_f32 packs accumulators (a0,a1),(a2,a3): 164 FMA -> 82.
//  - branchless activation av = m*sigma(m*acc)+(1-m) (r5-validated).
// Matvec VALU: ~328 -> ~90 insts/wave. Epilogue unchanged (redundant
// per-wave c/h state for pred; DPP wave-sum; wave 0 also stores h).

typedef __attribute__((ext_vector_type(4))) float f4;
typedef __attribute__((ext_vector_type(2))) float f2;

namespace {
constexpr int kB = 256;
constexpr int kT = 1024;
constexpr int kI = 8;
constexpr int kH = 164;
constexpr int kG = 4 * kH;                     // 656
constexpr int kThreads = 704;                  // 11 waves
constexpr int kRegC = 16;                      // pinned f4-quads (cols 0..63)
constexpr int kStrBase = kRegC * 4;            // 64
constexpr int kStrC = 10;                      // streamed quads (cols 64..103)
constexpr int kLdsBase = kStrBase + kStrC * 4; // 104
constexpr int kLdsC = (kH - kLdsBase) / 4;     // 15 planes (cols 104..163)
constexpr int kQ = kH / 4;                     // 41 h-quads
constexpr float kThresh = 0.1f;

__device__ __forceinline__ float rlane(float v, int l) {
    return __int_as_float(__builtin_amdgcn_readlane(__float_as_int(v), l));
}
template <int CTRL>
__device__ __forceinline__ float dpp_add(float x) {
    int t = __builtin_amdgcn_update_dpp(0, __float_as_int(x), CTRL, 0xf, 0xf, true);
    return __int_as_float(t);
}
// full-wave sum, result broadcast via lane 63
__device__ __forceinline__ float wave_sum(float x) {
    x += dpp_add<0x111>(x);   // row_shr:1
    x += dpp_add<0x112>(x);   // row_shr:2
    x += dpp_add<0x114>(x);   // row_shr:4
    x += dpp_add<0x118>(x);   // row_shr:8
    x += dpp_add<0x142>(x);   // row_bcast:15
    x += dpp_add<0x143>(x);   // row_bcast:31
    return rlane(x, 63);
}
// packed fp32 FMA: a.lo += w.lo*h.lo; a.hi += w.hi*h.hi  (VOP3P)
__device__ __forceinline__ void pkfma(f2& a, f2 w, f2 h) {
    asm("v_pk_fma_f32 %0, %1, %2, %0" : "+v"(a) : "v"(w), "v"(h));
}
// rcp + one Newton iteration: ~0.5 ulp at 3 instructions
__device__ __forceinline__ float fast_rcp(float d) {
    float r = __builtin_amdgcn_rcpf(d);
    float e = fmaf(-d, r, 1.0f);
    return fmaf(r, e, r);
}
// sigma(x), overflow-safe (clamp inf exp before Newton step)
__device__ __forceinline__ float sigm_c(float x) {
    float e = fminf(__expf(-x), 3.0e38f);
    return fast_rcp(1.0f + e);
}
// tanh(x) = 2*sigma(2x) - 1
__device__ __forceinline__ float tanh_c(float x) {
    return fmaf(2.0f, sigm_c(2.0f * x), -1.0f);
}
} // namespace

__global__
__attribute__((amdgpu_flat_work_group_size(kThreads, kThreads)))
__attribute__((amdgpu_waves_per_eu(3, 3)))
void lstm_anom_kernel(
    const float* __restrict__ x,     // (B,T,I)
    const float* __restrict__ Wih,   // (4H,I)
    const float* __restrict__ Whh,   // (4H,H)
    const float* __restrict__ bih,   // (4H)
    const float* __restrict__ bhh,   // (4H)
    const float* __restrict__ Wout,  // (1,H)
    const float* __restrict__ bout,  // (1)
    float* __restrict__ out)         // preds (B,T) then flags (B,T)
{
    __shared__ f4    wp[kLdsC * kG];    // 15*656*16 = 157440 B
    __shared__ float gates[2][kG];      // 5248 B
    __shared__ f4    hL[kQ];            // 656 B   (total 163344 B)

    const int tid  = threadIdx.x;
    const int lane = tid & 63;
    const int b    = blockIdx.x;
    const int jj   = (tid < kG) ? tid : (kG - 1);
    const bool is_tanh = (jj >= 2 * kH) && (jj < 3 * kH);
    // branchless activation constants: av = m*sigma(m*acc) + (1-m)
    const float am = is_tanh ? 2.0f : 1.0f;
    const float ao = 1.0f - am;

    // ---- stage W_hh tail planes (cols 104..163) + zero h ----
    for (int i = tid; i < kLdsC * kG; i += kThreads) {
        const int c = i / kG, r = i - c * kG;
        wp[i] = *(const f4*)(Whh + (size_t)r * kH + kLdsBase + 4 * c);
    }
    if (tid < kQ) hL[tid] = (f4){0.f, 0.f, 0.f, 0.f};

    // ---- pinned weights: cols 0..63 as 32 f2 pairs + W_ih (2 f4) ----
    const f2* wr2 = (const f2*)(Whh + (size_t)jj * kH);
    f2 p00 = wr2[0],  p01 = wr2[1],  p02 = wr2[2],  p03 = wr2[3];
    f2 p04 = wr2[4],  p05 = wr2[5],  p06 = wr2[6],  p07 = wr2[7];
    f2 p08 = wr2[8],  p09 = wr2[9],  p10 = wr2[10], p11 = wr2[11];
    f2 p12 = wr2[12], p13 = wr2[13], p14 = wr2[14], p15 = wr2[15];
    f2 p16 = wr2[16], p17 = wr2[17], p18 = wr2[18], p19 = wr2[19];
    f2 p20 = wr2[20], p21 = wr2[21], p22 = wr2[22], p23 = wr2[23];
    f2 p24 = wr2[24], p25 = wr2[25], p26 = wr2[26], p27 = wr2[27];
    f2 p28 = wr2[28], p29 = wr2[29], p30 = wr2[30], p31 = wr2[31];
    asm volatile("" : "+v"(p00), "+v"(p01), "+v"(p02), "+v"(p03),
                      "+v"(p04), "+v"(p05), "+v"(p06), "+v"(p07),
                      "+v"(p08), "+v"(p09), "+v"(p10), "+v"(p11),
                      "+v"(p12), "+v"(p13), "+v"(p14), "+v"(p15));
    asm volatile("" : "+v"(p16), "+v"(p17), "+v"(p18), "+v"(p19),
                      "+v"(p20), "+v"(p21), "+v"(p22), "+v"(p23),
                      "+v"(p24), "+v"(p25), "+v"(p26), "+v"(p27),
                      "+v"(p28), "+v"(p29), "+v"(p30), "+v"(p31));
    f4 wih0 = ((const f4*)(Wih + (size_t)jj * kI))[0];
    f4 wih1 = ((const f4*)(Wih + (size_t)jj * kI))[1];
    asm volatile("" : "+v"(wih0), "+v"(wih1));
    float bsum = bih[jj] + bhh[jj];
    const int u2 = (lane < kH - 128) ? (128 + lane) : (kH - 1); // clamp
    float wo0 = Wout[lane];
    float wo1 = Wout[64 + lane];
    float wo2 = (128 + lane < kH) ? Wout[128 + lane] : 0.0f;    // kills dup
    asm volatile("" : "+v"(bsum), "+v"(wo0), "+v"(wo1), "+v"(wo2));
    const float bo = bout[0];

    // streamed cols 64..103: 10 loads, all base + immediate offset
    const f4* ws = (const f4*)(Whh + (size_t)jj * kH + kStrBase);

    // redundant per-wave state (for pred + wave0 h-store)
    float vc0 = 0.f, vc1 = 0.f, vc2 = 0.f;
    float vh0 = 0.f, vh1 = 0.f, vh2 = 0.f;
    float pred = 0.f;

    const float* xb = x + (size_t)b * kT * kI;
    float* pred_out = out + (size_t)b * kT;
    float* flag_out = out + (size_t)kB * kT + (size_t)b * kT;

    // 3 LDS base pointers keep tail ds_read offsets within imm range
    const f4* wt0 = wp + jj;
    const f4* wt5 = wp + 5 * kG + jj;
    const f4* wtA = wp + 10 * kG + jj;

    f4 xa = ((const f4*)xb)[0];
    f4 xc = ((const f4*)xb)[1];

    __syncthreads();

    for (int t = 0; t < kT; ++t) {
        // ---- stream issue (consumed last) ----
        f4 sA0 = ws[0], sA1 = ws[1], sA2 = ws[2], sA3 = ws[3], sA4 = ws[4];
        f4 sB0 = ws[5], sB1 = ws[6], sB2 = ws[7], sB3 = ws[8], sB4 = ws[9];

        const bool  anom = (t > 0) && (fabsf(pred - xa.x) > kThresh);
        const float x0e  = anom ? pred : xa.x;

        // ---- x-part ----
        float a0 = fmaf(x0e, wih0.x, bsum);
        float a1 = xa.y * wih0.y;
        float a2 = xa.z * wih0.z;
        float a3 = xa.w * wih0.w;
        a0 = fmaf(xc.x, wih1.x, a0);
        a1 = fmaf(xc.y, wih1.y, a1);
        a2 = fmaf(xc.z, wih1.z, a2);
        a3 = fmaf(xc.w, wih1.w, a3);
        f2 a01 = {a0, a1};
        f2 a23 = {a2, a3};

        // prefetch x[t+1] (uniform across block — single line)
        const f4* nx = (const f4*)(xb + (size_t)((t + 1 < kT) ? t + 1 : t) * kI);
        f4 na = nx[0];
        f4 nc = nx[1];

        // quad Q: h[4Q..4Q+3] broadcast from LDS (uniform addr), 2 pk_fma
        #define GRPQ(WLO, WHI, Q) { \
            const f4 hq = hL[Q]; \
            const f2 hlo = {hq.x, hq.y}; \
            const f2 hhi = {hq.z, hq.w}; \
            pkfma(a01, (WLO), hlo); \
            pkfma(a23, (WHI), hhi); }

        // ---- pinned quads 0..15 (cols 0..63) under stream latency ----
        GRPQ(p00, p01, 0)  GRPQ(p02, p03, 1)  GRPQ(p04, p05, 2)  GRPQ(p06, p07, 3)
        GRPQ(p08, p09, 4)  GRPQ(p10, p11, 5)  GRPQ(p12, p13, 6)  GRPQ(p14, p15, 7)
        GRPQ(p16, p17, 8)  GRPQ(p18, p19, 9)  GRPQ(p20, p21, 10) GRPQ(p22, p23, 11)
        GRPQ(p24, p25, 12) GRPQ(p26, p27, 13) GRPQ(p28, p29, 14) GRPQ(p30, p31, 15)

        // ---- LDS tail quads 26..40 (cols 104..163): more stream cover ----
        #pragma unroll
        for (int c = 0; c < kLdsC; ++c) {
            const f4 w = (c < 5)  ? wt0[c * kG]
                       : (c < 10) ? wt5[(c - 5) * kG]
                                  : wtA[(c - 10) * kG];
            const f2 wlo = {w.x, w.y};
            const f2 whi = {w.z, w.w};
            GRPQ(wlo, whi, kLdsBase / 4 + c)
        }

        // ---- streamed quads 16..25 (cols 64..103), loads landed ----
        #define SGRP(S, Q) { \
            const f2 wlo = {(S).x, (S).y}; \
            const f2 whi = {(S).z, (S).w}; \
            GRPQ(wlo, whi, Q) }
        SGRP(sA0, 16) SGRP(sA1, 17) SGRP(sA2, 18) SGRP(sA3, 19) SGRP(sA4, 20)
        SGRP(sB0, 21) SGRP(sB1, 22) SGRP(sB2, 23) SGRP(sB3, 24) SGRP(sB4, 25)
        #undef SGRP
        #undef GRPQ

        // ---- branchless activation: av = m*sigma(m*acc) + (1-m) ----
        const float acc = (a01.x + a01.y) + (a23.x + a23.y);
        const float av  = fmaf(am, sigm_c(am * acc), ao);

        float* gw = gates[t & 1];
        if (tid < kG) gw[jj] = av;
        __syncthreads();                       // barrier 1: gates ready

        // ---- redundant cell/h update in every wave ----
        const float* gb = gates[t & 1];
        float iv0 = gb[lane],          iv1 = gb[64 + lane],          iv2 = gb[u2];
        float fv0 = gb[kH + lane],     fv1 = gb[kH + 64 + lane],     fv2 = gb[kH + u2];
        float gv0 = gb[2*kH + lane],   gv1 = gb[2*kH + 64 + lane],   gv2 = gb[2*kH + u2];
        float ov0 = gb[3*kH + lane],   ov1 = gb[3*kH + 64 + lane],   ov2 = gb[3*kH + u2];
        vc0 = fmaf(fv0, vc0, iv0 * gv0);  vh0 = ov0 * tanh_c(vc0);
        vc1 = fmaf(fv1, vc1, iv1 * gv1);  vh1 = ov1 * tanh_c(vc1);
        vc2 = fmaf(fv2, vc2, iv2 * gv2);  vh2 = ov2 * tanh_c(vc2);

        // wave 0 publishes h(t) for next step's matvec
        if (tid < 64) {
            float* hw = (float*)hL;
            hw[lane]      = vh0;
            hw[64 + lane] = vh1;
            if (lane < kH - 128) hw[128 + lane] = vh2;
        }

        // ---- pred (redundant per wave; DPP reduce, VALU only) ----
        const float p = fmaf(vh0, wo0, fmaf(vh1, wo1, vh2 * wo2));
        pred = wave_sum(p) + bo;

        __syncthreads();                       // barrier 2: h visible

        if (tid == 0) {
            pred_out[t] = pred;
            flag_out[t] = anom ? 1.0f : 0.0f;
        }
        xa = na;
        xc = nc;
    }
}

extern "C" void kernel_launch(void* const* d_in, const int* in_sizes, int n_in,
                              void* d_out, int out_size, void* d_ws, size_t ws_size,
                              hipStream_t stream) {
    const float* x    = (const float*)d_in[0];
    const float* Wih  = (const float*)d_in[1];
    const float* Whh  = (const float*)d_in[2];
    const float* bih  = (const float*)d_in[3];
    const float* bhh  = (const float*)d_in[4];
    const float* Wout = (const float*)d_in[5];
    const float* bout = (const float*)d_in[6];
    lstm_anom_kernel<<<dim3(kB), dim3(kThreads), 0, stream>>>(
        x, Wih, Whh, bih, bhh, Wout, bout, (float*)d_out);
}